// Round 4
// baseline (916.526 us; speedup 1.0000x reference)
//
#include <hip/hip_runtime.h>
#include <math.h>
#include <string.h>

// V2VNetFusion on MI355X, round 8: K=16 chunks -> 2 blocks/CU + pipeline.
// Round-7 (463us) was LDS-throughput-bound at 1 block/CU (152KB dbuf):
// only 2 waves/SIMD to hide ds_read latency + per-round kb0 ramp.
// This round halves the pipeline working set via mfma_f32_16x16x16f16:
// 16-ch chunks (input 19.6KB + weights 18.4KB, dbuf = 76KB < 80KB) ->
// 2 blocks/CU, 16 waves/CU. Same total LDS bytes; the co-resident block
// fills LDS-pipe stalls, overlaps barrier drains and staging ramps.
// Also: zero-page DMA source for OOB rows (no LDS pre-zero), 1-bit XOR
// swizzle (2-way conflicts = free), conflict-free lane-major b64 weights.
#define HH 200
#define WW 352
#define HWSZ (HH*WW)          // 70400
#define CHW (64L*HWSZ)        // one (64,H,W) tensor, elems

enum { EPI_MSG=0, EPI_GATES=1, EPI_CAND=2 };

typedef __attribute__((ext_vector_type(4))) _Float16 f16x4;
typedef __attribute__((ext_vector_type(4))) float f32x4;
typedef __attribute__((ext_vector_type(4))) unsigned int uint4v;
typedef __attribute__((ext_vector_type(4))) unsigned short ushort4v;

__device__ __forceinline__ unsigned short f2h(float f) {
    _Float16 h = (_Float16)f;                    // v_cvt_f16_f32 (RTE)
    return __builtin_bit_cast(unsigned short, h);
}
__device__ __forceinline__ float h2f(unsigned short u) {
    return (float)__builtin_bit_cast(_Float16, u);
}

// global->LDS DMA, 16B per lane. LDS dest = wave-uniform base + lane*16.
__device__ __forceinline__ void load_lds16(const unsigned short* g,
                                           unsigned short* l) {
    __builtin_amdgcn_global_load_lds(
        (const __attribute__((address_space(1))) unsigned int*)g,
        (__attribute__((address_space(3))) unsigned int*)l, 16, 0, 0);
}

// Prepack conv weights to f16, LDS-ready lane-major K16 layout:
// [cogrp64][kc16][sh(9)][cf(4)][lane(64)][4ch]; 9216 f16 per (cogrp,kc).
// lane = q*16+n16 -> co = cogrp*64 + cf*16+n16, ch = kc*16 + q*4+j.
// msg: 1x8, gates: 2x12, cand: 1x12 chunks.  Tail threads zero the
// 256B zero-page (DMA source for OOB rows/halo).
__global__ void prepack_k(const float* __restrict__ mw,
                          const float* __restrict__ gw,
                          const float* __restrict__ cw,
                          unsigned short* __restrict__ pw,
                          unsigned short* __restrict__ zp)
{
    const int MSG_I = 8*9216;         // 73728
    const int GAT_I = 24*9216;        // 221184
    const int CAN_I = 12*9216;        // 110592
    const int TOTAL = MSG_I + GAT_I + CAN_I;   // 405504
    int idx = blockIdx.x*256 + threadIdx.x;
    if (idx >= TOTAL) {
        int r = idx - TOTAL;
        if (r < 128) zp[r] = 0;
        return;
    }
    const float* w; int cin, nkc, rel; unsigned short* base;
    if (idx < MSG_I)              { w=mw; cin=128; nkc=8;  rel=idx;              base=pw; }
    else if (idx < MSG_I+GAT_I)   { w=gw; cin=192; nkc=12; rel=idx-MSG_I;        base=pw+73728; }
    else                          { w=cw; cin=192; nkc=12; rel=idx-MSG_I-GAT_I;  base=pw+294912; }
    int chunk = rel / 9216, r = rel - chunk*9216;
    int j = r & 3, lane = (r >> 2) & 63, cfsh = r >> 8;   // cfsh 0..35
    int cf = cfsh & 3, sh = cfsh >> 2;
    int q = lane >> 4, n16 = lane & 15;
    int co_l = cf*16 + n16, ch = q*4 + j;
    int cogrp = chunk / nkc, kc = chunk - cogrp*nkc;
    float f = w[(((long)(cogrp*64 + co_l))*cin + kc*16 + ch)*9 + sh];
    base[(size_t)chunk*9216 + r] = f2h(f);
}

// Convert x (2 agents x 4 t) fp32 planar -> f16 interleaved [t][half][pix][32].
__global__ void convert_all_k(const float* __restrict__ x,
                              unsigned short* __restrict__ xb0_all,
                              unsigned short* __restrict__ xb1_all)
{
    int idx = blockIdx.x*256 + threadIdx.x;      // 4,505,600 total
    int cp   = idx & 15;
    int rest = idx >> 4;
    int px4  = rest % 17600;
    int r2   = rest / 17600;                      // 0..15
    int hb = r2 & 1, ag = (r2 >> 1) & 1, t = r2 >> 2;
    const float* src = x + ((size_t)(ag*4 + t))*CHW
                         + (size_t)(hb*32 + 2*cp)*HWSZ + (size_t)px4*4;
    float4 a = *(const float4*)src;
    float4 b = *(const float4*)(src + HWSZ);
    unsigned int* dst = (unsigned int*)((ag ? xb1_all : xb0_all)
                        + (size_t)t*CHW + (size_t)hb*HWSZ*32) + (size_t)px4*64 + cp;
    dst[0]  = (unsigned)f2h(a.x) | ((unsigned)f2h(b.x) << 16);
    dst[16] = (unsigned)f2h(a.y) | ((unsigned)f2h(b.y) << 16);
    dst[32] = (unsigned)f2h(a.z) | ((unsigned)f2h(b.z) << 16);
    dst[48] = (unsigned)f2h(a.w) | ((unsigned)f2h(b.w) << 16);
}

// Block: 64 out-ch x (16 rows x 32 cols), 512 thr = 8 waves; wave w = rows
// 2w,2w+1, all 64 co.  kc loop over 16-ch chunks (nkc = 8 or 12).
// LDS: 2x input [612 pos][16ch] (19584 B) + 2x weights [9][4][64][4ch]
// (18432 B) = 76032 B -> 2 blocks/CU, 16 waves.
// Per pair of kc: haloWrite(b0); barrier; stage(kc+1->b1); compute(b0);
// haloWrite(b1); barrier; stage(kc+2->b0); compute(b1).  DMAs issued
// after the barrier stay in flight across the whole compute phase.
template<int EPI>
__global__ __launch_bounds__(512, 4)
void conv_mfma_k(const unsigned short* __restrict__ seg0b,
                 const unsigned short* __restrict__ seg1b,
                 const unsigned short* __restrict__ seg2b,
                 int nkc, int nkc_stride, int grp_base,
                 const unsigned short* __restrict__ pw,
                 const unsigned short* __restrict__ zp,
                 const float* __restrict__ bias,
                 const unsigned short* e_hb,     // f16 interl. h_{t-1} (null @t=0)
                 const unsigned short* __restrict__ e_updb, // CAND: upd f16 interl.
                 float* out_f,                   // CAND: out[t] fp32 planar
                 unsigned short* out_b,          // MSG: aggb(t<3) GATES: rhb CAND: hb
                 unsigned short* out_b2)         // MSG: aggb3    GATES: updb
{
    __shared__ unsigned short s_in0[612*16];   // [pos=row*34+col][16ch] 19584 B
    __shared__ unsigned short s_in1[612*16];
    __shared__ unsigned short s_w0[9*4*64*4];  // [sh][cf][lane][4ch]   18432 B
    __shared__ unsigned short s_w1[9*4*64*4];

    const int tid  = threadIdx.x;
    const int lane = tid & 63;
    const int wv   = tid >> 6;
    const int n16  = lane & 15;
    const int q    = lane >> 4;

    const int z = blockIdx.z;
    int grp, ts = 0;
    if (EPI == EPI_MSG) { ts = z; grp = 0; } else grp = z + grp_base;

    const unsigned short* s0 = seg0b + (EPI==EPI_MSG ? (size_t)ts*CHW : 0);
    const unsigned short* s1 = seg1b + (EPI==EPI_MSG ? (size_t)ts*CHW : 0);
    unsigned short* ob = out_b;
    if (EPI == EPI_MSG) ob = (ts < 3) ? out_b + (size_t)ts*CHW : out_b2;

    const int x0p = blockIdx.x * 32;
    const int y0  = blockIdx.y * 16;

    // ---- halo descriptor: ring = 100 pos x 2 granules(16B); tid<200.
    int hdst = 0, hsig = 0; size_t hsrc = 0; bool hval = false;
    if (tid < 200) {
        int pp = tid >> 1, hh = tid & 1;
        int row, col;
        if (pp < 34)      { row = 0;  col = pp; }
        else if (pp < 68) { row = 17; col = pp - 34; }
        else { int k = pp - 68; row = 1 + (k >> 1); col = (k & 1) * 33; }
        int pos = row*34 + col;
        int gy = y0 + row - 1, gx = x0p + col - 1;
        int sg = (pos >> 2) & 1;
        hsig = sg;
        hdst = pos*16 + hh*8;
        int g = hh ^ sg;                       // global pair this slot holds
        if ((unsigned)gy < (unsigned)HH && (unsigned)gx < (unsigned)WW) {
            hval = true;
            hsrc = (size_t)(gy*WW + gx)*32 + (size_t)g*8;
        }
    }
    (void)hsig;

    // chunk kc (16 ch): seg = kc>>2 (x / agg / h-or-rh), half = (kc>>1)&1,
    // 16B-pair within pixel granule = kc&1.
    auto srcof = [&](int kc) -> const unsigned short* {
        const unsigned short* sp = (kc < 4) ? s0 : (kc < 8) ? s1 : seg2b;
        return sp + (size_t)((kc >> 1) & 1)*HWSZ*32 + (size_t)(kc & 1)*16;
    };

    // ---- stage chunk kc into (bin, bw); halo granule -> hreg.
    // Interior rows + weights via global_load_lds (LDS linear dest,
    // per-lane inverse-swizzled source; OOB rows -> zero page).
    auto stage = [&](int kc, unsigned short* bin, unsigned short* bw, uint4v& hreg) {
        const unsigned short* src = srcof(kc);
#pragma unroll
        for (int i = 0; i < 2; ++i) {          // interior: row r = 1+2wv+i
            const int r  = 1 + wv*2 + i;
            const int gy = y0 + r - 1;
            const int pr = lane >> 1;
            const int pos = r*34 + 1 + pr;
            const int g = (lane & 1) ^ ((pos >> 2) & 1);
            const unsigned short* sp = ((unsigned)gy < (unsigned)HH)
                ? src + ((size_t)(gy*WW + x0p + pr))*32 + (size_t)g*8
                : zp;
            load_lds16(sp, &bin[(size_t)(r*34 + 1)*16]);
        }
        {   // weights: 18 chunks of 1024B
            const unsigned short* wsrc = pw + (size_t)(grp*nkc_stride + kc)*9216;
#pragma unroll
            for (int i = 0; i < 3; ++i) {
                const int u = wv + 8*i;
                if (u < 18)
                    load_lds16(wsrc + (size_t)u*512 + (size_t)lane*8,
                               &bw[(size_t)u*512]);
            }
        }
        if (tid < 200)
            hreg = *(const uint4v*)(hval ? src + hsrc : zp);
    };

    f32x4 acc[4][4];
#pragma unroll
    for (int cf=0; cf<4; ++cf)
#pragma unroll
        for (int p=0; p<4; ++p) acc[cf][p] = (f32x4){0.f,0.f,0.f,0.f};

    auto compute = [&](const unsigned short* sin, const unsigned short* swt) {
#pragma unroll
        for (int ky = 0; ky < 3; ++ky) {
#pragma unroll
            for (int kx = 0; kx < 3; ++kx) {
                const int sh = ky*3 + kx;
                f16x4 aw[4];
#pragma unroll
                for (int cf = 0; cf < 4; ++cf)
                    aw[cf] = *(const f16x4*)&swt[((sh*4 + cf)*64 + lane)*4];
#pragma unroll
                for (int p = 0; p < 4; ++p) {
                    const int rl = 2*wv + (p >> 1) + ky;
                    const int cl = 16*(p & 1) + n16 + kx;
                    const int pos = rl*34 + cl;
                    const int h = (q >> 1) ^ ((pos >> 2) & 1);
                    const f16x4 bfr = *(const f16x4*)&sin[(size_t)pos*16 + h*8 + (q & 1)*4];
#pragma unroll
                    for (int cf = 0; cf < 4; ++cf)
                        acc[cf][p] = __builtin_amdgcn_mfma_f32_16x16x16f16(
                                         aw[cf], bfr, acc[cf][p], 0, 0, 0);
                }
            }
        }
    };

    uint4v h0, h1;
    stage(0, s_in0, s_w0, h0);                 // prologue (exposed once)

    for (int kc = 0; kc < nkc; kc += 2) {      // nkc even (8 or 12)
        // ===== phase A: ready buf0 (kc), prefetch kc+1 -> buf1
        if (tid < 200) *(uint4v*)&s_in0[hdst] = h0;   // waits halo load
        __syncthreads();          // kc's DMAs + halo writes visible
        stage(kc + 1, s_in1, s_w1, h1);
        __builtin_amdgcn_sched_barrier(0);     // issue DMAs before reads
        compute(s_in0, s_w0);
        // ===== phase B: ready buf1 (kc+1), prefetch kc+2 -> buf0
        if (tid < 200) *(uint4v*)&s_in1[hdst] = h1;
        __syncthreads();
        if (kc + 2 < nkc) {
            stage(kc + 2, s_in0, s_w0, h0);
            __builtin_amdgcn_sched_barrier(0);
        }
        compute(s_in1, s_w1);
    }

    // ---- epilogue. C/D: pixel = lane&15, co = (lane>>4)*4 + reg
#pragma unroll
    for (int cf = 0; cf < 4; ++cf) {
        const int half   = cf >> 1;                // 32-ch half within co64
        const int cobase = grp*64 + cf*16 + q*4;   // global co of reg 0
        const int cmod   = (cf & 1)*16 + q*4;      // co within 32-plane
#pragma unroll
        for (int p = 0; p < 4; ++p) {
            const int row = y0 + 2*wv + (p >> 1);
            const int col = x0p + 16*(p & 1) + n16;
            if (row >= HH) continue;
            const long pix = (long)row*WW + col;
            const size_t iidx = (((size_t)half*HWSZ + pix) << 5) + cmod;
            float v[4];
#pragma unroll
            for (int r = 0; r < 4; ++r) v[r] = acc[cf][p][r] + bias[cobase + r];

            if (EPI == EPI_MSG) {
                ushort4v xv = *(const ushort4v*)&s0[iidx];
                ushort4v s;
#pragma unroll
                for (int r = 0; r < 4; ++r)
                    s[r] = f2h(0.5f*(h2f(xv[r]) + v[r]));
                *(ushort4v*)&ob[iidx] = s;
            } else if (EPI == EPI_GATES) {
                if (grp == 0) {  // reset block -> rh = sigmoid * h
                    ushort4v hv = e_hb ? *(const ushort4v*)&e_hb[iidx]
                                       : (ushort4v){0,0,0,0};
                    ushort4v s;
#pragma unroll
                    for (int r = 0; r < 4; ++r) {
                        float g = 1.f/(1.f + __expf(-v[r]));
                        s[r] = f2h(g * h2f(hv[r]));
                    }
                    *(ushort4v*)&out_b[iidx] = s;
                } else {         // update block -> updb
                    ushort4v s;
#pragma unroll
                    for (int r = 0; r < 4; ++r)
                        s[r] = f2h(1.f/(1.f + __expf(-v[r])));
                    *(ushort4v*)&out_b2[iidx] = s;
                }
            } else {             // CAND: h_next -> out fp32 planar + hb f16
                ushort4v uv = *(const ushort4v*)&e_updb[iidx];
                ushort4v hv = e_hb ? *(const ushort4v*)&e_hb[iidx]
                                   : (ushort4v){0,0,0,0};
                ushort4v s;
#pragma unroll
                for (int r = 0; r < 4; ++r) {
                    float cnm = tanhf(v[r]);
                    float u   = h2f(uv[r]);
                    float hn  = (1.f - u)*h2f(hv[r]) + u*cnm;
                    out_f[(long)(cobase+r)*HWSZ + pix] = hn;
                    s[r] = f2h(hn);
                }
                *(ushort4v*)&out_b[iidx] = s;
            }
        }
    }
}

// ws (u16 units): xb0_all 4C | aggb3 C | rhb C | updb C | hb C | pw 405504
//   | zp 128  = 72.9 MB.   d_out aliases: xb1_all = out[0..1] (dead until
//   step 0 writes out[0]), aggb[0..2] = out[2..3].
extern "C" void kernel_launch(void* const* d_in, const int* in_sizes, int n_in,
                              void* d_out, int out_size, void* d_ws, size_t ws_size,
                              hipStream_t stream)
{
    const float* x       = (const float*)d_in[0];
    const float* msg_w   = (const float*)d_in[1];
    const float* msg_b   = (const float*)d_in[2];
    const float* gates_w = (const float*)d_in[3];
    const float* gates_b = (const float*)d_in[4];
    const float* can_w   = (const float*)d_in[5];
    const float* can_b   = (const float*)d_in[6];
    float* out = (float*)d_out;

    unsigned short* W       = (unsigned short*)d_ws;
    unsigned short* xb0_all = W;                  // [4][2][HWSZ][32]
    unsigned short* aggb3   = W + 4*CHW;
    unsigned short* rhb     = W + 5*CHW;
    unsigned short* updb    = W + 6*CHW;
    unsigned short* hb      = W + 7*CHW;
    unsigned short* pw      = W + 8*CHW;          // 405504 u16
    unsigned short* pw_msg  = pw;
    unsigned short* pw_gat  = pw + 73728;
    unsigned short* pw_can  = pw + 294912;
    unsigned short* zp      = pw + 405504;        // 128 u16 zero page

    unsigned short* outU16   = (unsigned short*)d_out;
    unsigned short* xb1_all  = outU16;            // 4*CHW u16 = out[0..1]
    unsigned short* aggbase  = outU16 + 4*CHW;    // aggb[0..2] = out[2..3]

    prepack_k<<<dim3(1585), dim3(256), 0, stream>>>(msg_w, gates_w, can_w, pw, zp);
    convert_all_k<<<dim3(17600), dim3(256), 0, stream>>>(x, xb0_all, xb1_all);

    // msg for all 4 t in one dispatch: Cin=[x0|x1], Cout=64 -> aggb[t]
    conv_mfma_k<EPI_MSG><<<dim3(11,13,4), dim3(512), 0, stream>>>(
        xb0_all, xb1_all, nullptr, 8, 8, 0, pw_msg, zp, msg_b,
        nullptr, nullptr, nullptr, aggbase, aggb3);

    for (int t = 0; t < 4; ++t) {
        const unsigned short* xt  = xb0_all + (size_t)t*CHW;
        const unsigned short* agt = (t < 3) ? aggbase + (size_t)t*CHW : aggb3;
        const unsigned short* hprev = t ? hb : nullptr;

        // gates: Cin=[x|agg|h], Cout=128; z=0 -> reset (co 0..63),
        // z=1 -> update (co 64..127). t=0: h==0 -> reset*h==0 and
        // CAND(nkc=8) never reads rhb, so launch update half only.
        conv_mfma_k<EPI_GATES><<<dim3(11,13, t ? 2 : 1), dim3(512), 0, stream>>>(
            xt, agt, hb, t ? 12 : 8, 12, t ? 0 : 1, pw_gat, zp, gates_b,
            hprev, nullptr, nullptr, rhb, updb);
        // cand: Cin=[x|agg|rh], Cout=64 -> out[t] fp32 + hb f16
        conv_mfma_k<EPI_CAND><<<dim3(11,13,1), dim3(512), 0, stream>>>(
            xt, agt, rhb, t ? 12 : 8, 12, 0, pw_can, zp, can_b,
            hprev, updb, out + (size_t)t*CHW, hb, nullptr);
    }
}

// Round 5
// 428.439 us; speedup vs baseline: 2.1392x; 2.1392x over previous
//
#include <hip/hip_runtime.h>
#include <math.h>
#include <string.h>

// V2VNetFusion on MI355X, round 9: cf=4 K=32 pipeline AT 2 blocks/CU.
// Round-8 lessons: (a) 16x16x16 MFMA issues at ~16x16x32 cost -> never
// drop K below 32; (b) staging must read full 64B pixel granules
// (32B-strided reads amplified FETCH 104->245MB).
// Round-7 (463us) was sound but ran 1 block/CU (152KB LDS): CAND idled
// half the GPU (143 blocks), GATES paid 2-round tails, and a lone block
// can't hide its own barrier drains.
// This round: 256-thread blocks (4 waves), 8-row x 32-col tiles, cf=4,
// K=32.  LDS = input dbuf 2x21760 + weights sbuf 36864 = 80384 B ->
// 2 blocks/CU (8 waves).  Input pipelined via __syncthreads schedule
// (DMAs issued post-barrier fly across the whole compute phase);
// single-buffered weight DMA is exposed ~0.3us/kb but hides under the
// co-resident block.  Zero-page halo (no LDS pre-zero); interior rows
// never OOB with 8-row tiles.
#define HH 200
#define WW 352
#define HWSZ (HH*WW)          // 70400
#define CHW (64L*HWSZ)        // one (64,H,W) tensor, elems

enum { EPI_MSG=0, EPI_GATES=1, EPI_CAND=2 };

typedef __attribute__((ext_vector_type(8))) _Float16 f16x8;
typedef __attribute__((ext_vector_type(4))) float f32x4;
typedef __attribute__((ext_vector_type(4))) unsigned int uint4v;
typedef __attribute__((ext_vector_type(4))) unsigned short ushort4v;

__device__ __forceinline__ unsigned short f2h(float f) {
    _Float16 h = (_Float16)f;                    // v_cvt_f16_f32 (RTE)
    return __builtin_bit_cast(unsigned short, h);
}
__device__ __forceinline__ float h2f(unsigned short u) {
    return (float)__builtin_bit_cast(_Float16, u);
}

// global->LDS DMA, 16B per lane. LDS dest = wave-uniform base + lane*16.
__device__ __forceinline__ void load_lds16(const unsigned short* g,
                                           unsigned short* l) {
    __builtin_amdgcn_global_load_lds(
        (const __attribute__((address_space(1))) unsigned int*)g,
        (__attribute__((address_space(3))) unsigned int*)l, 16, 0, 0);
}

// Prepack conv weights to f16, LDS-ready lane-major layout, cf=4:
// [cogrp64][kb][sh(9)][cf(4)][lane(64)][8ch]; 18432 f16 per (cogrp,kb).
// lane = q*16+n16 -> co = cogrp*64 + cf*16+n16, ch = q*8+j.
// msg: 1x4, gates: 2x6, cand: 1x6 chunks.  Tail threads zero the 256B
// zero-page (DMA/reg source for OOB halo).
__global__ void prepack_k(const float* __restrict__ mw,
                          const float* __restrict__ gw,
                          const float* __restrict__ cw,
                          unsigned short* __restrict__ pw,
                          unsigned short* __restrict__ zp)
{
    const int MSG_I = 4*18432;        // 73728
    const int GAT_I = 12*18432;       // 221184
    const int CAN_I = 6*18432;        // 110592
    const int TOTAL = MSG_I + GAT_I + CAN_I;   // 405504
    int idx = blockIdx.x*256 + threadIdx.x;
    if (idx >= TOTAL) {
        int r = idx - TOTAL;
        if (r < 128) zp[r] = 0;
        return;
    }
    const float* w; int cin, nkb, rel; unsigned short* base;
    if (idx < MSG_I)              { w=mw; cin=128; nkb=4; rel=idx;              base=pw; }
    else if (idx < MSG_I+GAT_I)   { w=gw; cin=192; nkb=6; rel=idx-MSG_I;        base=pw+73728; }
    else                          { w=cw; cin=192; nkb=6; rel=idx-MSG_I-GAT_I;  base=pw+294912; }
    int chunk = rel / 18432, r = rel - chunk*18432;
    int j = r & 7, lane = (r >> 3) & 63, cfsh = r >> 9;   // cfsh 0..35
    int cf = cfsh & 3, sh = cfsh >> 2;
    int q = lane >> 4, n16 = lane & 15;
    int co_l = cf*16 + n16, ch = q*8 + j;
    int cogrp = chunk / nkb, kb = chunk - cogrp*nkb;
    float f = w[(((long)(cogrp*64 + co_l))*cin + kb*32 + ch)*9 + sh];
    base[(size_t)chunk*18432 + r] = f2h(f);
}

// Convert x (2 agents x 4 t) fp32 planar -> f16 interleaved [t][half][pix][32].
__global__ void convert_all_k(const float* __restrict__ x,
                              unsigned short* __restrict__ xb0_all,
                              unsigned short* __restrict__ xb1_all)
{
    int idx = blockIdx.x*256 + threadIdx.x;      // 4,505,600 total
    int cp   = idx & 15;
    int rest = idx >> 4;
    int px4  = rest % 17600;
    int r2   = rest / 17600;                      // 0..15
    int hb = r2 & 1, ag = (r2 >> 1) & 1, t = r2 >> 2;
    const float* src = x + ((size_t)(ag*4 + t))*CHW
                         + (size_t)(hb*32 + 2*cp)*HWSZ + (size_t)px4*4;
    float4 a = *(const float4*)src;
    float4 b = *(const float4*)(src + HWSZ);
    unsigned int* dst = (unsigned int*)((ag ? xb1_all : xb0_all)
                        + (size_t)t*CHW + (size_t)hb*HWSZ*32) + (size_t)px4*64 + cp;
    dst[0]  = (unsigned)f2h(a.x) | ((unsigned)f2h(b.x) << 16);
    dst[16] = (unsigned)f2h(a.y) | ((unsigned)f2h(b.y) << 16);
    dst[32] = (unsigned)f2h(a.z) | ((unsigned)f2h(b.z) << 16);
    dst[48] = (unsigned)f2h(a.w) | ((unsigned)f2h(b.w) << 16);
}

// Block: 64 out-ch x (8 rows x 32 cols), 256 thr = 4 waves; wave w = rows
// 2w,2w+1, all 64 co (cf=0..3).  LDS: 2x input [10][34][32] f16 XOR-swz
// (21760 B) + 1x weights [9][4][64][8] (36864 B) = 80384 B -> 2 blocks/CU.
template<int EPI>
__global__ __launch_bounds__(256, 2)
void conv_mfma_k(const unsigned short* __restrict__ seg0b,
                 const unsigned short* __restrict__ seg1b,
                 const unsigned short* __restrict__ seg2b,
                 int nkb, int nkb_stride, int grp_base,
                 const unsigned short* __restrict__ pw,
                 const unsigned short* __restrict__ zp,
                 const float* __restrict__ bias,
                 const unsigned short* e_hb,     // f16 interl. h_{t-1} (null @t=0)
                 const unsigned short* __restrict__ e_updb, // CAND: upd f16 interl.
                 float* out_f,                   // CAND: out[t] fp32 planar
                 unsigned short* out_b,          // MSG: aggb(t<3) GATES: rhb CAND: hb
                 unsigned short* out_b2)         // MSG: aggb3    GATES: updb
{
    __shared__ unsigned short s_in0[340*32];   // [pos=row*34+col][32ch] 21760 B
    __shared__ unsigned short s_in1[340*32];
    __shared__ unsigned short s_w[9*4*64*8];   // [sh][cf][lane][8]     36864 B

    const int tid  = threadIdx.x;
    const int lane = tid & 63;
    const int wv   = tid >> 6;                 // 0..3
    const int n16  = lane & 15;
    const int q    = lane >> 4;

    const int z = blockIdx.z;
    int grp, ts = 0;
    if (EPI == EPI_MSG) { ts = z; grp = 0; } else grp = z + grp_base;

    const unsigned short* s0 = seg0b + (EPI==EPI_MSG ? (size_t)ts*CHW : 0);
    const unsigned short* s1 = seg1b + (EPI==EPI_MSG ? (size_t)ts*CHW : 0);
    unsigned short* ob = out_b;
    if (EPI == EPI_MSG) ob = (ts < 3) ? out_b + (size_t)ts*CHW : out_b2;

    const int x0p = blockIdx.x * 32;
    const int y0  = blockIdx.y * 8;

    // ---- halo descriptors: ring = 84 pos x 4 granules = 336 slots.
    // Thread tid owns slot tid (<336) and slot tid+256 (tid<80).
    int hdst0 = 0, hdst1 = 0; size_t hsrc0 = 0, hsrc1 = 0;
    bool hval0 = false, hval1 = false;
    {
        auto hcalc = [&](int s, int& hdst, size_t& hsrc, bool& hval) {
            int hp = s >> 2, gs = s & 3;
            int row, col;
            if (hp < 34)      { row = 0; col = hp; }
            else if (hp < 68) { row = 9; col = hp - 34; }
            else { int k = hp - 68; row = 1 + (k >> 1); col = (k & 1) * 33; }
            int pos = row*34 + col;
            int gy = y0 + row - 1, gx = x0p + col - 1;
            hdst = (pos << 5) + (gs << 3);
            int g = (gs ^ pos ^ (pos >> 2)) & 3;
            if ((unsigned)gy < (unsigned)HH && (unsigned)gx < (unsigned)WW) {
                hval = true;
                hsrc = ((size_t)(gy*WW + gx) << 5) + (size_t)(g << 3);
            }
        };
        if (tid < 336) hcalc(tid, hdst0, hsrc0, hval0);
        if (tid < 80)  hcalc(tid + 256, hdst1, hsrc1, hval1);
    }

    auto srcof = [&](int kb) -> const unsigned short* {
        return ((kb < 2) ? s0 : (kb < 4) ? s1 : seg2b) + (size_t)(kb & 1)*HWSZ*32;
    };

    struct HV { uint4v a, b; };
    auto halo_load = [&](int kb, HV& h) {
        const unsigned short* src = srcof(kb);
        if (tid < 336) h.a = *(const uint4v*)(hval0 ? src + hsrc0 : zp);
        if (tid < 80)  h.b = *(const uint4v*)(hval1 ? src + hsrc1 : zp);
    };
    auto halo_write = [&](unsigned short* bin, const HV& h) {
        if (tid < 336) *(uint4v*)&bin[hdst0] = h.a;
        if (tid < 80)  *(uint4v*)&bin[hdst1] = h.b;
    };

    // interior: 8 rows x 2 col-halves = 16 wave-chunks (full 64B granules,
    // inverse-swizzled source, linear LDS dest). Rows never OOB (8-row tile).
    auto stage_in = [&](int kb, unsigned short* bin) {
        const unsigned short* src = srcof(kb);
#pragma unroll
        for (int j = 0; j < 4; ++j) {
            const int c    = wv + 4*j;         // 0..15
            const int row  = 1 + (c >> 1);     // 1..8
            const int colh = c & 1;
            const int gy   = y0 + row - 1;     // in [0,199] always
            const int p0   = row*34 + 1 + colh*16;
            const int pl   = p0 + (lane >> 2);
            const int g    = ((lane & 3) ^ pl ^ (pl >> 2)) & 3;
            const int gx   = x0p + colh*16 + (lane >> 2);
            load_lds16(src + (((size_t)(gy*WW + gx)) << 5) + (g << 3),
                       &bin[(size_t)p0 << 5]);
        }
    };
    auto stage_w = [&](int kb) {
        const unsigned short* wsrc = pw + (size_t)(grp*nkb_stride + kb)*18432;
#pragma unroll
        for (int i = 0; i < 9; ++i) {
            const int u = wv + 4*i;            // 0..35 exactly
            load_lds16(wsrc + (size_t)u*512 + (size_t)lane*8, &s_w[(size_t)u*512]);
        }
    };

    f32x4 acc[4][4];
#pragma unroll
    for (int cf=0; cf<4; ++cf)
#pragma unroll
        for (int p=0; p<4; ++p) acc[cf][p] = (f32x4){0.f,0.f,0.f,0.f};

    auto compute = [&](const unsigned short* sin) {
#pragma unroll
        for (int ky = 0; ky < 3; ++ky) {
#pragma unroll
            for (int kx = 0; kx < 3; ++kx) {
                const int sh = ky*3 + kx;
                f16x8 aw[4];
#pragma unroll
                for (int cf = 0; cf < 4; ++cf)
                    aw[cf] = *(const f16x8*)&s_w[((sh*4 + cf)*64 + lane)*8];
#pragma unroll
                for (int p = 0; p < 4; ++p) {
                    const int rl = 2*wv + (p >> 1) + ky;
                    const int cl = 16*(p & 1) + n16 + kx;
                    const int pos = rl*34 + cl;
                    const int sw = (q ^ pos ^ (pos >> 2)) & 3;
                    f16x8 bfr = *(const f16x8*)&sin[(pos << 5) + (sw << 3)];
#pragma unroll
                    for (int cf = 0; cf < 4; ++cf)
                        acc[cf][p] = __builtin_amdgcn_mfma_f32_16x16x32_f16(
                                         aw[cf], bfr, acc[cf][p], 0, 0, 0);
                }
            }
        }
    };

    HV h0, h1;
    stage_in(0, s_in0);          // prologue: kb=0 input + weights + halo
    stage_w(0);
    halo_load(0, h0);

    for (int kb = 0; kb < nkb; kb += 2) {      // nkb even (4 or 6)
        // ===== phase A: buf0 = kb
        halo_write(s_in0, h0);                 // waits h0 (vmcnt dep)
        __syncthreads();                       // kb in+w DMAs landed, halo visible
        halo_load(kb + 1, h1);
        stage_in(kb + 1, s_in1);               // flies across compute
        __builtin_amdgcn_sched_barrier(0);
        compute(s_in0);
        __syncthreads();                       // all waves done reading s_w(kb)
        stage_w(kb + 1);
        // ===== phase B: buf1 = kb+1
        halo_write(s_in1, h1);
        __syncthreads();                       // kb+1 in+w DMAs landed
        if (kb + 2 < nkb) {
            halo_load(kb + 2, h0);
            stage_in(kb + 2, s_in0);
            __builtin_amdgcn_sched_barrier(0);
        }
        compute(s_in1);
        __syncthreads();
        if (kb + 2 < nkb) stage_w(kb + 2);
    }

    // ---- epilogue. C/D: pixel = lane&15, co = (lane>>4)*4 + reg
#pragma unroll
    for (int cf = 0; cf < 4; ++cf) {
        const int half   = cf >> 1;                // 32-ch half within co64
        const int cobase = grp*64 + cf*16 + q*4;   // global co of reg 0
        const int cmod   = (cf & 1)*16 + q*4;      // co within 32-plane
#pragma unroll
        for (int p = 0; p < 4; ++p) {
            const int row = y0 + 2*wv + (p >> 1);
            const int col = x0p + 16*(p & 1) + n16;
            if (row >= HH) continue;
            const long pix = (long)row*WW + col;
            const size_t iidx = (((size_t)half*HWSZ + pix) << 5) + cmod;
            float v[4];
#pragma unroll
            for (int r = 0; r < 4; ++r) v[r] = acc[cf][p][r] + bias[cobase + r];

            if (EPI == EPI_MSG) {
                ushort4v xv = *(const ushort4v*)&s0[iidx];
                ushort4v s;
#pragma unroll
                for (int r = 0; r < 4; ++r)
                    s[r] = f2h(0.5f*(h2f(xv[r]) + v[r]));
                *(ushort4v*)&ob[iidx] = s;
            } else if (EPI == EPI_GATES) {
                if (grp == 0) {  // reset block -> rh = sigmoid * h
                    ushort4v hv = e_hb ? *(const ushort4v*)&e_hb[iidx]
                                       : (ushort4v){0,0,0,0};
                    ushort4v s;
#pragma unroll
                    for (int r = 0; r < 4; ++r) {
                        float g = 1.f/(1.f + __expf(-v[r]));
                        s[r] = f2h(g * h2f(hv[r]));
                    }
                    *(ushort4v*)&out_b[iidx] = s;
                } else {         // update block -> updb
                    ushort4v s;
#pragma unroll
                    for (int r = 0; r < 4; ++r)
                        s[r] = f2h(1.f/(1.f + __expf(-v[r])));
                    *(ushort4v*)&out_b2[iidx] = s;
                }
            } else {             // CAND: h_next -> out fp32 planar + hb f16
                ushort4v uv = *(const ushort4v*)&e_updb[iidx];
                ushort4v hv = e_hb ? *(const ushort4v*)&e_hb[iidx]
                                   : (ushort4v){0,0,0,0};
                ushort4v s;
#pragma unroll
                for (int r = 0; r < 4; ++r) {
                    float cnm = tanhf(v[r]);
                    float u   = h2f(uv[r]);
                    float hn  = (1.f - u)*h2f(hv[r]) + u*cnm;
                    out_f[(long)(cobase+r)*HWSZ + pix] = hn;
                    s[r] = f2h(hn);
                }
                *(ushort4v*)&out_b[iidx] = s;
            }
        }
    }
}

// ws (u16 units): xb0_all 4C | aggb3 C | rhb C | updb C | hb C | pw 405504
//   | zp 128  = 72.9 MB.   d_out aliases: xb1_all = out[0..1] (dead until
//   step 0 writes out[0]), aggb[0..2] = out[2..3].
extern "C" void kernel_launch(void* const* d_in, const int* in_sizes, int n_in,
                              void* d_out, int out_size, void* d_ws, size_t ws_size,
                              hipStream_t stream)
{
    const float* x       = (const float*)d_in[0];
    const float* msg_w   = (const float*)d_in[1];
    const float* msg_b   = (const float*)d_in[2];
    const float* gates_w = (const float*)d_in[3];
    const float* gates_b = (const float*)d_in[4];
    const float* can_w   = (const float*)d_in[5];
    const float* can_b   = (const float*)d_in[6];
    float* out = (float*)d_out;

    unsigned short* W       = (unsigned short*)d_ws;
    unsigned short* xb0_all = W;                  // [4][2][HWSZ][32]
    unsigned short* aggb3   = W + 4*CHW;
    unsigned short* rhb     = W + 5*CHW;
    unsigned short* updb    = W + 6*CHW;
    unsigned short* hb      = W + 7*CHW;
    unsigned short* pw      = W + 8*CHW;          // 405504 u16
    unsigned short* pw_msg  = pw;
    unsigned short* pw_gat  = pw + 73728;
    unsigned short* pw_can  = pw + 294912;
    unsigned short* zp      = pw + 405504;        // 128 u16 zero page

    unsigned short* outU16   = (unsigned short*)d_out;
    unsigned short* xb1_all  = outU16;            // 4*CHW u16 = out[0..1]
    unsigned short* aggbase  = outU16 + 4*CHW;    // aggb[0..2] = out[2..3]

    prepack_k<<<dim3(1585), dim3(256), 0, stream>>>(msg_w, gates_w, can_w, pw, zp);
    convert_all_k<<<dim3(17600), dim3(256), 0, stream>>>(x, xb0_all, xb1_all);

    // msg for all 4 t in one dispatch: Cin=[x0|x1], Cout=64 -> aggb[t]
    conv_mfma_k<EPI_MSG><<<dim3(11,25,4), dim3(256), 0, stream>>>(
        xb0_all, xb1_all, nullptr, 4, 4, 0, pw_msg, zp, msg_b,
        nullptr, nullptr, nullptr, aggbase, aggb3);

    for (int t = 0; t < 4; ++t) {
        const unsigned short* xt  = xb0_all + (size_t)t*CHW;
        const unsigned short* agt = (t < 3) ? aggbase + (size_t)t*CHW : aggb3;
        const unsigned short* hprev = t ? hb : nullptr;

        // gates: Cin=[x|agg|h], Cout=128; z=0 -> reset (co 0..63),
        // z=1 -> update (co 64..127). t=0: h==0 -> reset*h==0 and
        // CAND(nkb=4) never reads rhb, so launch update half only.
        conv_mfma_k<EPI_GATES><<<dim3(11,25, t ? 2 : 1), dim3(256), 0, stream>>>(
            xt, agt, hb, t ? 6 : 4, 6, t ? 0 : 1, pw_gat, zp, gates_b,
            hprev, nullptr, nullptr, rhb, updb);
        // cand: Cin=[x|agg|rh], Cout=64 -> out[t] fp32 + hb f16
        conv_mfma_k<EPI_CAND><<<dim3(11,25,1), dim3(256), 0, stream>>>(
            xt, agt, rhb, t ? 6 : 4, 6, 0, pw_can, zp, can_b,
            hprev, updb, out + (size_t)t*CHW, hb, nullptr);
    }
}